// Round 3
// baseline (631.136 us; speedup 1.0000x reference)
//
#include <hip/hip_runtime.h>
#include <hip/hip_bf16.h>

#define NN   13824     // 24^3 neurons
#define BB   256       // batch
#define KDIM 512       // input dim
#define ODIM 1000      // output dim
#define CUBE 24
#define KS   16        // out-gemm split-K

typedef short bf8 __attribute__((ext_vector_type(8)));     // 8 bf16 (4 VGPRs)
typedef float f32x4 __attribute__((ext_vector_type(4)));   // MFMA acc

__device__ __forceinline__ float fast_tanh(float a) {
    float e = __expf(2.0f * a);
    return 1.0f - 2.0f / (e + 1.0f);
}
__device__ __forceinline__ float bf_lo(unsigned u) { return __uint_as_float(u << 16); }
__device__ __forceinline__ float bf_hi(unsigned u) { return __uint_as_float(u & 0xffff0000u); }
__device__ __forceinline__ unsigned short bf_rne(float f) {
    unsigned u = __float_as_uint(f);
    u += 0x7fffu + ((u >> 16) & 1u);
    return (unsigned short)(u >> 16);
}
// packed fp32x2 -> bf16x2 via v_cvt_pk_bf16_f32 (one inst on gfx950)
__device__ __forceinline__ unsigned pk_bf16(float lo, float hi) {
    union { __hip_bfloat162 h; unsigned u; } cv;
    cv.h = __float22bfloat162_rn(make_float2(lo, hi));
    return cv.u;
}
__device__ __forceinline__ bf8 cvt8(float4 a, float4 b) {
    union { bf8 v; unsigned u[4]; } r;
    r.u[0] = pk_bf16(a.x, a.y);
    r.u[1] = pk_bf16(a.z, a.w);
    r.u[2] = pk_bf16(b.x, b.y);
    r.u[3] = pk_bf16(b.z, b.w);
    return r.v;
}

// ---------------------------------------------------------------------------
// x (fp32 [256][512]) -> x_bf (bf16 packed dwords)
// ---------------------------------------------------------------------------
__global__ __launch_bounds__(256) void xbf_kernel(
    const float* __restrict__ x, unsigned* __restrict__ xb)
{
    int i = blockIdx.x * 256 + threadIdx.x;
    float2 v = *(const float2*)&x[(size_t)i * 2];
    xb[i] = pk_bf16(v.x, v.y);
}

// ---------------------------------------------------------------------------
// xproj via MFMA, software-pipelined, fused h1 = tanh(xp) epilogue.
// grid 864 (16-n tiles), 4 waves; wave w covers b = w*64..w*64+63 (4 tiles).
// ---------------------------------------------------------------------------
__global__ __launch_bounds__(256) void xproj_mfma(
    const float* __restrict__ w_in, const float* __restrict__ bias,
    const short* __restrict__ xbf, unsigned short* __restrict__ xp,
    unsigned short* __restrict__ h1)
{
    const int tid = threadIdx.x, w = tid >> 6, lane = tid & 63;
    const int quad = lane >> 4, l16 = lane & 15;
    const int n0 = blockIdx.x * 16;
    const float* __restrict__ arow = &w_in[(size_t)(n0 + l16) * KDIM];

    f32x4 acc[4] = {};

    int ka = quad * 8;
    float4 a0 = *(const float4*)&arow[ka];
    float4 a1 = *(const float4*)&arow[ka + 4];
    bf8 bb[4];
#pragma unroll
    for (int j = 0; j < 4; ++j)
        bb[j] = *(const bf8*)&xbf[(size_t)(w * 64 + j * 16 + l16) * KDIM + ka];

    for (int it = 0; it < 16; ++it) {
        float4 na0{}, na1{}; bf8 nb[4] = {};
        if (it < 15) {
            const int nka = ka + 32;
            na0 = *(const float4*)&arow[nka];
            na1 = *(const float4*)&arow[nka + 4];
#pragma unroll
            for (int j = 0; j < 4; ++j)
                nb[j] = *(const bf8*)&xbf[(size_t)(w * 64 + j * 16 + l16) * KDIM + nka];
        }
        bf8 af = cvt8(a0, a1);
#pragma unroll
        for (int j = 0; j < 4; ++j)
            acc[j] = __builtin_amdgcn_mfma_f32_16x16x32_bf16(af, bb[j], acc[j], 0, 0, 0);
        a0 = na0; a1 = na1;
#pragma unroll
        for (int j = 0; j < 4; ++j) bb[j] = nb[j];
        ka += 32;
    }

#pragma unroll
    for (int j = 0; j < 4; ++j) {
        const int b = w * 64 + j * 16 + l16;
#pragma unroll
        for (int r = 0; r < 4; ++r) {
            const int n = n0 + quad * 4 + r;
            const float v = acc[j][r] + bias[n];
            xp[(size_t)n * BB + b] = bf_rne(v);
            h1[(size_t)n * BB + b] = bf_rne(fast_tanh(v));
        }
    }
}

// ---------------------------------------------------------------------------
// Recurrent step v7: MLP fix. v6's per-xi xp load was the YOUNGEST
// outstanding vmem at its use -> s_waitcnt vmcnt(0) drained the whole plane
// prefetch pipeline every iteration. v7: (1) xp preloaded in prologue;
// (2) PACKED ring-6 of dwords (54 VGPR vs 90 for float2 ring-5), unpack on
// use (VALU has 85% headroom); (3) prefetch distance 3 (27 loads in flight
// during compute); (4) launch_bounds(256,5) caps VGPR at 102 so all 1152
// blocks (4.5/CU) are co-resident in one round (v6 at ~110 VGPR had a
// 2-round tail). Keeps v6's y-pair L1 sharing + zhi slab -> XCD pinning.
// ---------------------------------------------------------------------------
__device__ __forceinline__ void load_plane_pk(
    const unsigned* __restrict__ h32, int z, int y, int xx, int dof,
    unsigned* pk)
{
#pragma unroll
    for (int j = 0; j < 9; ++j) {
        const int dz = j / 3 - 1, dy = j % 3 - 1;
        const int zz = z + dz, yy = y + dy;
        const bool valid = (xx >= 0) & (xx < CUBE) & (zz >= 0) & (zz < CUBE) &
                           (yy >= 0) & (yy < CUBE);   // wave-uniform
        unsigned v = 0u;
        if (valid) v = h32[(size_t)((zz * 24 + yy) * 24 + xx) * 128 + dof];
        pk[j] = v;
    }
}

__global__ __launch_bounds__(256, 5) void step_kernel(
    const unsigned* __restrict__ hprev, const unsigned* __restrict__ xp,
    const float* __restrict__ wl, unsigned* __restrict__ hnext)
{
    const int tid  = threadIdx.x;
    const int wid  = __builtin_amdgcn_readfirstlane(tid >> 6);  // 0..3
    const int wvb  = wid & 1;          // batch half
    const int yoff = wid >> 1;         // y within the pair
    const int lane = tid & 63;

    const int bid   = blockIdx.x;
    const int zhi   = bid & 7;
    const int inner = bid >> 3;       // 0..143
    const int yp    = inner % 12;
    const int r     = inner / 12;     // 0..11
    const int xc    = r & 3;
    const int zlo   = r >> 2;
    const int z     = zhi * 3 + zlo;
    const int y     = yp * 2 + yoff;

    const int x0   = xc * 6;
    const int dof  = wvb * 64 + lane;  // dword offset (2 batch elems)
    const int n0   = (z * 24 + y) * 24 + x0;

    // packed ring-6: slot s holds plane x0-1+rel, s = rel % 6
    unsigned ring[6][9];
    load_plane_pk(hprev, z, y, x0 - 1, dof, ring[0]);
    load_plane_pk(hprev, z, y, x0,     dof, ring[1]);
    load_plane_pk(hprev, z, y, x0 + 1, dof, ring[2]);
    load_plane_pk(hprev, z, y, x0 + 2, dof, ring[3]);
    load_plane_pk(hprev, z, y, x0 + 3, dof, ring[4]);

    unsigned xpv[6];
#pragma unroll
    for (int xi = 0; xi < 6; ++xi)
        xpv[xi] = xp[(size_t)(n0 + xi) * 128 + dof];

#pragma unroll
    for (int xi = 0; xi < 6; ++xi) {
        // prefetch plane rel xi+5 (x = x0+xi+4), distance-3 ahead of use
        if (xi <= 2)
            load_plane_pk(hprev, z, y, x0 + xi + 4, dof, ring[(xi + 5) % 6]);

        const int n = n0 + xi;                        // wave-uniform
        const float* __restrict__ wn = &wl[(size_t)n * 27];
        const unsigned* pm = ring[xi % 6];
        const unsigned* pc = ring[(xi + 1) % 6];
        const unsigned* pp = ring[(xi + 2) % 6];

        float2 acc = make_float2(bf_lo(xpv[xi]), bf_hi(xpv[xi]));
#pragma unroll
        for (int j = 0; j < 9; ++j) {
            const float w0 = wn[3 * j + 0];
            const float w1 = wn[3 * j + 1];
            const float w2 = wn[3 * j + 2];
            acc.x += w0 * bf_lo(pm[j]) + w1 * bf_lo(pc[j]) + w2 * bf_lo(pp[j]);
            acc.y += w0 * bf_hi(pm[j]) + w1 * bf_hi(pc[j]) + w2 * bf_hi(pp[j]);
        }
        hnext[(size_t)n * 128 + dof] = pk_bf16(fast_tanh(acc.x), fast_tanh(acc.y));
    }
}

// ---------------------------------------------------------------------------
// Transpose h[k][b] -> hT[b][k] (bf16), 64x64 tiles via LDS.
// ---------------------------------------------------------------------------
__global__ __launch_bounds__(256) void transpose_kernel(
    const unsigned* __restrict__ h32, unsigned* __restrict__ hT32)
{
    __shared__ unsigned short T[64][66];
    const int tid = threadIdx.x;
    const int rr = tid >> 2, g = tid & 3;
    const int k0 = blockIdx.x * 64, b0 = blockIdx.y * 64;
#pragma unroll
    for (int i = 0; i < 8; ++i) {
        unsigned d = h32[(size_t)(k0 + rr) * 128 + b0 / 2 + g * 8 + i];
        const int bl = (g * 8 + i) * 2;
        T[bl][rr]     = (unsigned short)(d & 0xffffu);
        T[bl + 1][rr] = (unsigned short)(d >> 16);
    }
    __syncthreads();
#pragma unroll
    for (int i = 0; i < 8; ++i) {
        const int kl = (g * 8 + i) * 2;
        unsigned d = (unsigned)T[rr][kl] | ((unsigned)T[rr][kl + 1] << 16);
        hT32[(size_t)(b0 + rr) * (NN / 2) + k0 / 2 + g * 8 + i] = d;
    }
}

// ---------------------------------------------------------------------------
// Output GEMM v5: round-2 decomposition (4 waves share B via L1, A re-reads
// L2-local via same-XCD by-chunks) + DEPTH-2 software pipeline with NAMED
// stages and a dynamic step-2 loop (full unroll collapses the ring --
// round-1 lesson; runtime-indexed vector arrays go to scratch -- rule #20).
// Grid (8 o-blocks, 4 b-chunks, 16 K-chunks) = 512 blocks.
// ---------------------------------------------------------------------------
__global__ __launch_bounds__(256) void outgemm_mfma(
    const float* __restrict__ wout, const short* __restrict__ hT,
    float* __restrict__ part)
{
    const int tid = threadIdx.x, w = tid >> 6, lane = tid & 63;
    const int quad = lane >> 4, l16 = lane & 15;
    const int o0 = blockIdx.x * 128 + w * 32;
    const int kb = blockIdx.z * (NN / KS);   // 864-wide K chunk, 27 steps of 32
    const int b0 = blockIdx.y * 64;

    const int oa = o0 + l16, ob = o0 + 16 + l16;
    const bool av0 = oa < ODIM, av1 = ob < ODIM;
    const float* __restrict__ ar0 = &wout[(size_t)oa * NN];
    const float* __restrict__ ar1 = &wout[(size_t)ob * NN];
    const float4 z4 = {0.f, 0.f, 0.f, 0.f};

    f32x4 acc[2][4] = {};

    // stage 0 (even it), stage 1 (odd it) -- named, never runtime-indexed
    float4 s0a00, s0a01, s0a10, s0a11, s1a00, s1a01, s1a10, s1a11;
    bf8 s0b[4], s1b[4];

    {
        const int ka = kb + quad * 8;
        s0a00 = av0 ? *(const float4*)&ar0[ka]     : z4;
        s0a01 = av0 ? *(const float4*)&ar0[ka + 4] : z4;
        s0a10 = av1 ? *(const float4*)&ar1[ka]     : z4;
        s0a11 = av1 ? *(const float4*)&ar1[ka + 4] : z4;
#pragma unroll
        for (int j = 0; j < 4; ++j)
            s0b[j] = *(const bf8*)&hT[(size_t)(b0 + j * 16 + l16) * NN + ka];
        const int kc = ka + 32;
        s1a00 = av0 ? *(const float4*)&ar0[kc]     : z4;
        s1a01 = av0 ? *(const float4*)&ar0[kc + 4] : z4;
        s1a10 = av1 ? *(const float4*)&ar1[kc]     : z4;
        s1a11 = av1 ? *(const float4*)&ar1[kc + 4] : z4;
#pragma unroll
        for (int j = 0; j < 4; ++j)
            s1b[j] = *(const bf8*)&hT[(size_t)(b0 + j * 16 + l16) * NN + kc];
    }

    int ka = kb + quad * 8;
    for (int it = 0; it < 27; it += 2) {
        // ---- compute stage 0 (K index it) ----
        {
            bf8 af0 = cvt8(s0a00, s0a01);
            bf8 af1 = cvt8(s0a10, s0a11);
#pragma unroll
            for (int j = 0; j < 4; ++j) {
                acc[0][j] = __builtin_amdgcn_mfma_f32_16x16x32_bf16(af0, s0b[j], acc[0][j], 0, 0, 0);
                acc[1][j] = __builtin_amdgcn_mfma_f32_16x16x32_bf16(af1, s0b[j], acc[1][j], 0, 0, 0);
            }
        }
        if (it + 2 < 27) {               // refill stage 0 for K index it+2
            const int nk = ka + 64;
            s0a00 = av0 ? *(const float4*)&ar0[nk]     : z4;
            s0a01 = av0 ? *(const float4*)&ar0[nk + 4] : z4;
            s0a10 = av1 ? *(const float4*)&ar1[nk]     : z4;
            s0a11 = av1 ? *(const float4*)&ar1[nk + 4] : z4;
#pragma unroll
            for (int j = 0; j < 4; ++j)
                s0b[j] = *(const bf8*)&hT[(size_t)(b0 + j * 16 + l16) * NN + nk];
        }
        // ---- compute stage 1 (K index it+1) ----
        if (it + 1 < 27) {
            bf8 af0 = cvt8(s1a00, s1a01);
            bf8 af1 = cvt8(s1a10, s1a11);
#pragma unroll
            for (int j = 0; j < 4; ++j) {
                acc[0][j] = __builtin_amdgcn_mfma_f32_16x16x32_bf16(af0, s1b[j], acc[0][j], 0, 0, 0);
                acc[1][j] = __builtin_amdgcn_mfma_f32_16x16x32_bf16(af1, s1b[j], acc[1][j], 0, 0, 0);
            }
            if (it + 3 < 27) {           // refill stage 1 for K index it+3
                const int nk = ka + 96;
                s1a00 = av0 ? *(const float4*)&ar0[nk]     : z4;
                s1a01 = av0 ? *(const float4*)&ar0[nk + 4] : z4;
                s1a10 = av1 ? *(const float4*)&ar1[nk]     : z4;
                s1a11 = av1 ? *(const float4*)&ar1[nk + 4] : z4;
#pragma unroll
                for (int j = 0; j < 4; ++j)
                    s1b[j] = *(const bf8*)&hT[(size_t)(b0 + j * 16 + l16) * NN + nk];
            }
        }
        ka += 64;
    }

#pragma unroll
    for (int i = 0; i < 2; ++i)
#pragma unroll
        for (int j = 0; j < 4; ++j) {
            const int b = b0 + j * 16 + l16;
#pragma unroll
            for (int r = 0; r < 4; ++r) {
                const int o = o0 + i * 16 + quad * 4 + r;
                if (o < 1024)
                    part[((size_t)blockIdx.z * 1024 + o) * BB + b] = acc[i][j][r];
            }
        }
}

// out[b*1000+o] = bias[o] + sum_kc part[kc][o][b]; block per o, lanes = b.
__global__ __launch_bounds__(256) void reduce_kernel(
    const float* __restrict__ part, const float* __restrict__ bias,
    float* __restrict__ out)
{
    const int o = blockIdx.x, b = threadIdx.x;
    float s = bias[o];
#pragma unroll
    for (int kc = 0; kc < KS; ++kc)
        s += part[((size_t)kc * 1024 + o) * BB + b];
    out[(size_t)b * ODIM + o] = s;
}

extern "C" void kernel_launch(void* const* d_in, const int* in_sizes, int n_in,
                              void* d_out, int out_size, void* d_ws, size_t ws_size,
                              hipStream_t stream)
{
    const float* x       = (const float*)d_in[0];
    const float* w_in    = (const float*)d_in[1];
    const float* b_in    = (const float*)d_in[2];
    const float* w_local = (const float*)d_in[3];
    const float* w_out   = (const float*)d_in[4];
    const float* b_out   = (const float*)d_in[5];
    float* out = (float*)d_out;

    char* p = (char*)d_ws;
    unsigned short* xp_bf = (unsigned short*)p;          p += (size_t)NN * BB * 2;
    unsigned short* hA    = (unsigned short*)p;          p += (size_t)NN * BB * 2;
    unsigned short* hB    = (unsigned short*)p;          p += (size_t)NN * BB * 2;
    unsigned short* hT    = (unsigned short*)p;          p += (size_t)NN * BB * 2;
    unsigned short* x_bf  = (unsigned short*)p;          p += (size_t)BB * KDIM * 2;
    float*          part  = (float*)p;                   // KS*1024*BB floats

    xbf_kernel<<<256, 256, 0, stream>>>(x, (unsigned*)x_bf);
    xproj_mfma<<<864, 256, 0, stream>>>(w_in, b_in, (const short*)x_bf, xp_bf, hA);

    const unsigned* hp = (const unsigned*)hA;
    unsigned* hn = (unsigned*)hB;
    for (int s = 0; s < 29; ++s) {          // 29 odd -> final state in hB
        step_kernel<<<1152, 256, 0, stream>>>(hp, (const unsigned*)xp_bf, w_local, hn);
        unsigned* t = (unsigned*)hp; hp = hn; hn = t;
    }

    transpose_kernel<<<dim3(216, 4), 256, 0, stream>>>(hp, (unsigned*)hT);
    outgemm_mfma<<<dim3(8, 4, KS), 256, 0, stream>>>(w_out, (const short*)hT, part);
    reduce_kernel<<<ODIM, 256, 0, stream>>>(part, b_out, out);
}

// Round 5
// 552.949 us; speedup vs baseline: 1.1414x; 1.1414x over previous
//
#include <hip/hip_runtime.h>
#include <hip/hip_bf16.h>

#define NN   13824     // 24^3 neurons
#define BB   256       // batch
#define KDIM 512       // input dim
#define ODIM 1000      // output dim
#define CUBE 24
#define KS   16        // out-gemm split-K
#define ASTR 872       // LDS A row stride in shorts (1744B = 436 dw, %32=20)

typedef short bf8 __attribute__((ext_vector_type(8)));     // 8 bf16 (4 VGPRs)
typedef float f32x4 __attribute__((ext_vector_type(4)));   // MFMA acc

__device__ __forceinline__ float fast_tanh(float a) {
    float e = __expf(2.0f * a);
    return 1.0f - 2.0f / (e + 1.0f);
}
__device__ __forceinline__ float bf_lo(unsigned u) { return __uint_as_float(u << 16); }
__device__ __forceinline__ float bf_hi(unsigned u) { return __uint_as_float(u & 0xffff0000u); }
__device__ __forceinline__ unsigned short bf_rne(float f) {
    unsigned u = __float_as_uint(f);
    u += 0x7fffu + ((u >> 16) & 1u);
    return (unsigned short)(u >> 16);
}
// packed fp32x2 -> bf16x2 via v_cvt_pk_bf16_f32 (one inst on gfx950)
__device__ __forceinline__ unsigned pk_bf16(float lo, float hi) {
    union { __hip_bfloat162 h; unsigned u; } cv;
    cv.h = __float22bfloat162_rn(make_float2(lo, hi));
    return cv.u;
}
__device__ __forceinline__ bf8 cvt8(float4 a, float4 b) {
    union { bf8 v; unsigned u[4]; } r;
    r.u[0] = pk_bf16(a.x, a.y);
    r.u[1] = pk_bf16(a.z, a.w);
    r.u[2] = pk_bf16(b.x, b.y);
    r.u[3] = pk_bf16(b.z, b.w);
    return r.v;
}

// ---------------------------------------------------------------------------
// x (fp32 [256][512]) -> x_bf (bf16 packed dwords)
// ---------------------------------------------------------------------------
__global__ __launch_bounds__(256) void xbf_kernel(
    const float* __restrict__ x, unsigned* __restrict__ xb)
{
    int i = blockIdx.x * 256 + threadIdx.x;
    float2 v = *(const float2*)&x[(size_t)i * 2];
    xb[i] = pk_bf16(v.x, v.y);
}

// ---------------------------------------------------------------------------
// xproj via MFMA, software-pipelined, fused h1 = tanh(xp) epilogue.
// grid 864 (16-n tiles), 4 waves; wave w covers b = w*64..w*64+63 (4 tiles).
// ---------------------------------------------------------------------------
__global__ __launch_bounds__(256) void xproj_mfma(
    const float* __restrict__ w_in, const float* __restrict__ bias,
    const short* __restrict__ xbf, unsigned short* __restrict__ xp,
    unsigned short* __restrict__ h1)
{
    const int tid = threadIdx.x, w = tid >> 6, lane = tid & 63;
    const int quad = lane >> 4, l16 = lane & 15;
    const int n0 = blockIdx.x * 16;
    const float* __restrict__ arow = &w_in[(size_t)(n0 + l16) * KDIM];

    f32x4 acc[4] = {};

    int ka = quad * 8;
    float4 a0 = *(const float4*)&arow[ka];
    float4 a1 = *(const float4*)&arow[ka + 4];
    bf8 bb[4];
#pragma unroll
    for (int j = 0; j < 4; ++j)
        bb[j] = *(const bf8*)&xbf[(size_t)(w * 64 + j * 16 + l16) * KDIM + ka];

    for (int it = 0; it < 16; ++it) {
        float4 na0{}, na1{}; bf8 nb[4] = {};
        if (it < 15) {
            const int nka = ka + 32;
            na0 = *(const float4*)&arow[nka];
            na1 = *(const float4*)&arow[nka + 4];
#pragma unroll
            for (int j = 0; j < 4; ++j)
                nb[j] = *(const bf8*)&xbf[(size_t)(w * 64 + j * 16 + l16) * KDIM + nka];
        }
        bf8 af = cvt8(a0, a1);
#pragma unroll
        for (int j = 0; j < 4; ++j)
            acc[j] = __builtin_amdgcn_mfma_f32_16x16x32_bf16(af, bb[j], acc[j], 0, 0, 0);
        a0 = na0; a1 = na1;
#pragma unroll
        for (int j = 0; j < 4; ++j) bb[j] = nb[j];
        ka += 32;
    }

#pragma unroll
    for (int j = 0; j < 4; ++j) {
        const int b = w * 64 + j * 16 + l16;
#pragma unroll
        for (int r = 0; r < 4; ++r) {
            const int n = n0 + quad * 4 + r;
            const float v = acc[j][r] + bias[n];
            xp[(size_t)n * BB + b] = bf_rne(v);
            h1[(size_t)n * BB + b] = bf_rne(fast_tanh(v));
        }
    }
}

// ---------------------------------------------------------------------------
// Recurrent step v6 (round-2 measured best): float2 ring-5, x-chunk 6,
// 4-wave blocks pairing two adjacent y-lines (L1 sharing). 1152 blocks,
// bid&7 == z/3 -> XCD L2 slab pinning.
// ---------------------------------------------------------------------------
__device__ __forceinline__ void load_plane_f2(
    const unsigned* __restrict__ h32, int z, int y, int xx, int dof, float2* w9)
{
#pragma unroll
    for (int j = 0; j < 9; ++j) {
        const int dz = j / 3 - 1, dy = j % 3 - 1;
        const int zz = z + dz, yy = y + dy;
        const bool valid = (xx >= 0) & (xx < CUBE) & (zz >= 0) & (zz < CUBE) &
                           (yy >= 0) & (yy < CUBE);   // wave-uniform
        unsigned v = 0u;
        if (valid) v = h32[(size_t)((zz * 24 + yy) * 24 + xx) * 128 + dof];
        w9[j] = make_float2(bf_lo(v), bf_hi(v));
    }
}

__global__ __launch_bounds__(256) void step_kernel(
    const unsigned* __restrict__ hprev, const unsigned* __restrict__ xp,
    const float* __restrict__ wl, unsigned* __restrict__ hnext)
{
    const int tid  = threadIdx.x;
    const int wid  = __builtin_amdgcn_readfirstlane(tid >> 6);  // 0..3
    const int wvb  = wid & 1;          // batch half
    const int yoff = wid >> 1;         // y within the pair
    const int lane = tid & 63;

    const int bid   = blockIdx.x;
    const int zhi   = bid & 7;
    const int inner = bid >> 3;       // 0..143
    const int yp    = inner % 12;
    const int r     = inner / 12;     // 0..11
    const int xc    = r & 3;
    const int zlo   = r >> 2;
    const int z     = zhi * 3 + zlo;
    const int y     = yp * 2 + yoff;

    const int x0   = xc * 6;
    const int dof  = wvb * 64 + lane;  // dword offset (2 batch elems)

    float2 win[5][9];
    load_plane_f2(hprev, z, y, x0 - 1, dof, win[0]);
    load_plane_f2(hprev, z, y, x0,     dof, win[1]);
    load_plane_f2(hprev, z, y, x0 + 1, dof, win[2]);
    load_plane_f2(hprev, z, y, x0 + 2, dof, win[3]);

#pragma unroll
    for (int xi = 0; xi < 6; ++xi) {
        const int x = x0 + xi;
        if (xi <= 3)
            load_plane_f2(hprev, z, y, x + 3, dof, win[(xi + 4) % 5]);

        const int n = (z * 24 + y) * 24 + x;          // wave-uniform
        const float* __restrict__ wn = &wl[(size_t)n * 27];
        const unsigned xpv = xp[(size_t)n * 128 + dof];
        float2 acc = make_float2(bf_lo(xpv), bf_hi(xpv));

        const float2* pm = win[xi % 5];
        const float2* pc = win[(xi + 1) % 5];
        const float2* pp = win[(xi + 2) % 5];
#pragma unroll
        for (int j = 0; j < 9; ++j) {
            const float w0 = wn[3 * j + 0];
            const float w1 = wn[3 * j + 1];
            const float w2 = wn[3 * j + 2];
            acc.x += w0 * pm[j].x + w1 * pc[j].x + w2 * pp[j].x;
            acc.y += w0 * pm[j].y + w1 * pc[j].y + w2 * pp[j].y;
        }
        hnext[(size_t)n * 128 + dof] = pk_bf16(fast_tanh(acc.x), fast_tanh(acc.y));
    }
}

// ---------------------------------------------------------------------------
// Transpose h[k][b] -> hT[b][k] (bf16), 64x64 tiles via LDS.
// ---------------------------------------------------------------------------
__global__ __launch_bounds__(256) void transpose_kernel(
    const unsigned* __restrict__ h32, unsigned* __restrict__ hT32)
{
    __shared__ unsigned short T[64][66];
    const int tid = threadIdx.x;
    const int rr = tid >> 2, g = tid & 3;
    const int k0 = blockIdx.x * 64, b0 = blockIdx.y * 64;
#pragma unroll
    for (int i = 0; i < 8; ++i) {
        unsigned d = h32[(size_t)(k0 + rr) * 128 + b0 / 2 + g * 8 + i];
        const int bl = (g * 8 + i) * 2;
        T[bl][rr]     = (unsigned short)(d & 0xffffu);
        T[bl + 1][rr] = (unsigned short)(d >> 16);
    }
    __syncthreads();
#pragma unroll
    for (int i = 0; i < 8; ++i) {
        const int kl = (g * 8 + i) * 2;
        unsigned d = (unsigned)T[rr][kl] | ((unsigned)T[rr][kl + 1] << 16);
        hT32[(size_t)(b0 + rr) * (NN / 2) + k0 / 2 + g * 8 + i] = d;
    }
}

// ---------------------------------------------------------------------------
// Output GEMM v6b: LDS-staged A, swizzle bug fixed. Round-4's XOR swizzle
// assumed 128B-aligned row windows but the row stride (1728B) wasn't a
// multiple of 128 -> last-window offsets mapped past the row end (data
// corruption, absmax 0.33). Fix: NO XOR; pad row stride to 872 shorts
// (1744B = 436 dwords, 436 mod 32 = 20), so consecutive rows start 20 banks
// apart (period 8 covers all 32 banks) -> the 16-lane ds_read_b128 A-frag
// read is at the wave64 minimum of 8 dwords/bank (conflict-free).
// Block = 32o x 256b x 864k; A staged once (8 whole rows per wave,
// 1KB-contiguous global reads = long sequential HBM streams; A read exactly
// once globally). B (hT) keeps the proven depth-1 register pipeline;
// blockIdx.x = K-chunk so the 32 blocks sharing a B K-slice land on the
// same XCD. Grid (KS=16, 32 o-tiles) = 512 blocks, 2/CU (LDS 55808B).
// ---------------------------------------------------------------------------
__global__ __launch_bounds__(256) void outgemm_mfma(
    const float* __restrict__ wout, const short* __restrict__ hT,
    float* __restrict__ part)
{
    __shared__ unsigned short As[32 * ASTR];
    const int tid = threadIdx.x, w = tid >> 6, lane = tid & 63;
    const int quad = lane >> 4, l16 = lane & 15;
    const int kb = blockIdx.x * (NN / KS);    // 864-wide K chunk
    const int o0 = blockIdx.y * 32;
    const int b0 = w * 64;

    // ---- stage A: 8 rows per wave, 1KB-contiguous global reads ----
#pragma unroll
    for (int rr = 0; rr < 8; ++rr) {
        const int row = w * 8 + rr;
        const int o = o0 + row;
        const float* __restrict__ src = &wout[(size_t)o * NN + kb];
#pragma unroll
        for (int c = 0; c < 4; ++c) {
            const int col = c * 256 + lane * 4;     // floats within row
            if (c < 3 || lane < 24) {               // 864 = 3*256 + 96
                float4 v = {0.f, 0.f, 0.f, 0.f};
                if (o < ODIM) v = *(const float4*)&src[col];
                uint2 pk2 = make_uint2(pk_bf16(v.x, v.y), pk_bf16(v.z, v.w));
                *(uint2*)&As[(unsigned)row * ASTR + (unsigned)col] = pk2;
            }
        }
    }
    __syncthreads();

    // ---- compute: 27 kc of K=32; depth-1 B prefetch (registers) ----
    f32x4 acc[2][4] = {};

    bf8 bb[4];
    {
        const int ka = kb + quad * 8;
#pragma unroll
        for (int j = 0; j < 4; ++j)
            bb[j] = *(const bf8*)&hT[(size_t)(b0 + j * 16 + l16) * NN + ka];
    }

    const int r0 = l16, r1 = 16 + l16;

    for (int kc = 0; kc < 27; ++kc) {
        bf8 nb[4] = {};
        if (kc < 26) {
            const int ka = kb + (kc + 1) * 32 + quad * 8;
#pragma unroll
            for (int j = 0; j < 4; ++j)
                nb[j] = *(const bf8*)&hT[(size_t)(b0 + j * 16 + l16) * NN + ka];
        }
        const int cs = kc * 32 + quad * 8;           // short offset in row
        bf8 a0 = *(const bf8*)&As[(unsigned)r0 * ASTR + (unsigned)cs];
        bf8 a1 = *(const bf8*)&As[(unsigned)r1 * ASTR + (unsigned)cs];
#pragma unroll
        for (int j = 0; j < 4; ++j) {
            acc[0][j] = __builtin_amdgcn_mfma_f32_16x16x32_bf16(a0, bb[j], acc[0][j], 0, 0, 0);
            acc[1][j] = __builtin_amdgcn_mfma_f32_16x16x32_bf16(a1, bb[j], acc[1][j], 0, 0, 0);
        }
#pragma unroll
        for (int j = 0; j < 4; ++j) bb[j] = nb[j];
    }

#pragma unroll
    for (int i = 0; i < 2; ++i)
#pragma unroll
        for (int j = 0; j < 4; ++j) {
            const int b = b0 + j * 16 + l16;
#pragma unroll
            for (int r = 0; r < 4; ++r) {
                const int o = o0 + i * 16 + quad * 4 + r;
                part[((size_t)blockIdx.x * 1024 + o) * BB + b] = acc[i][j][r];
            }
        }
}

// out[b*1000+o] = bias[o] + sum_kc part[kc][o][b]; block per o, lanes = b.
__global__ __launch_bounds__(256) void reduce_kernel(
    const float* __restrict__ part, const float* __restrict__ bias,
    float* __restrict__ out)
{
    const int o = blockIdx.x, b = threadIdx.x;
    float s = bias[o];
#pragma unroll
    for (int kc = 0; kc < KS; ++kc)
        s += part[((size_t)kc * 1024 + o) * BB + b];
    out[(size_t)b * ODIM + o] = s;
}

extern "C" void kernel_launch(void* const* d_in, const int* in_sizes, int n_in,
                              void* d_out, int out_size, void* d_ws, size_t ws_size,
                              hipStream_t stream)
{
    const float* x       = (const float*)d_in[0];
    const float* w_in    = (const float*)d_in[1];
    const float* b_in    = (const float*)d_in[2];
    const float* w_local = (const float*)d_in[3];
    const float* w_out   = (const float*)d_in[4];
    const float* b_out   = (const float*)d_in[5];
    float* out = (float*)d_out;

    char* p = (char*)d_ws;
    unsigned short* xp_bf = (unsigned short*)p;          p += (size_t)NN * BB * 2;
    unsigned short* hA    = (unsigned short*)p;          p += (size_t)NN * BB * 2;
    unsigned short* hB    = (unsigned short*)p;          p += (size_t)NN * BB * 2;
    unsigned short* hT    = (unsigned short*)p;          p += (size_t)NN * BB * 2;
    unsigned short* x_bf  = (unsigned short*)p;          p += (size_t)BB * KDIM * 2;
    float*          part  = (float*)p;                   // KS*1024*BB floats

    xbf_kernel<<<256, 256, 0, stream>>>(x, (unsigned*)x_bf);
    xproj_mfma<<<864, 256, 0, stream>>>(w_in, b_in, (const short*)x_bf, xp_bf, hA);

    const unsigned* hp = (const unsigned*)hA;
    unsigned* hn = (unsigned*)hB;
    for (int s = 0; s < 29; ++s) {          // 29 odd -> final state in hB
        step_kernel<<<1152, 256, 0, stream>>>(hp, (const unsigned*)xp_bf, w_local, hn);
        unsigned* t = (unsigned*)hp; hp = hn; hn = t;
    }

    transpose_kernel<<<dim3(216, 4), 256, 0, stream>>>(hp, (unsigned*)hT);
    outgemm_mfma<<<dim3(KS, 32), 256, 0, stream>>>(w_out, (const short*)hT, part);
    reduce_kernel<<<ODIM, 256, 0, stream>>>(part, b_out, out);
}